// Round 9
// baseline (116.088 us; speedup 1.0000x reference)
//
#include <hip/hip_runtime.h>
#include <hip/hip_bf16.h>
#include <stdint.h>

#define N_NODES 50000
#define NE      1600000
#define DIM     128
#define HID     64

typedef __attribute__((ext_vector_type(8))) short bf16x8;
typedef __attribute__((ext_vector_type(4))) float f32x4;

// ---------------- JAX threefry2x32 core (bit-exact) ----------------
struct TF2 { uint32_t a, b; };

__host__ __device__ constexpr uint32_t rotl32(uint32_t x, int d) {
  return (x << d) | (x >> (32 - d));
}

__host__ __device__ constexpr TF2 threefry(uint32_t k0, uint32_t k1,
                                           uint32_t c0, uint32_t c1) {
  uint32_t ks[3] = { k0, k1, k0 ^ k1 ^ 0x1BD11BDAu };
  uint32_t x0 = c0 + ks[0], x1 = c1 + ks[1];
  const int rot[2][4] = { {13, 15, 26, 6}, {17, 29, 16, 24} };
  for (int i = 0; i < 5; ++i) {
    for (int r = 0; r < 4; ++r) {
      x0 += x1;
      x1 = rotl32(x1, rot[i & 1][r]);
      x1 ^= x0;
    }
    x0 += ks[(i + 1) % 3];
    x1 += ks[(i + 2) % 3] + (uint32_t)(i + 1);
  }
  return { x0, x1 };
}

// jax_threefry_partitionable split: nk_j = full threefry(key, (0, j))
constexpr TF2 SPA = threefry(0u, 42u, 0u, 0u);
constexpr TF2 SPB = threefry(0u, 42u, 0u, 1u);
constexpr uint32_t NK1_0 = SPA.a, NK1_1 = SPA.b;
constexpr uint32_t NK2_0 = SPB.a, NK2_1 = SPB.b;

// partitionable random_bits(32): bits = y0 ^ y1 of threefry(key, 0, i)
__device__ inline float gumbel_elem(uint32_t k0, uint32_t k1, uint32_t i) {
  TF2 t = threefry(k0, k1, 0u, i);
  uint32_t bits = t.a ^ t.b;
  float f = __uint_as_float((bits >> 9) | 0x3f800000u) - 1.0f;
  float u = fmaxf(1.1754943508222875e-38f, f + 1.1754943508222875e-38f);
  return -__logf(-__logf(u));   // v_log_f32 ~1 ulp; budget is 2e-2
}

__device__ inline unsigned short f2bf_rne(float f) {
  uint32_t u = __float_as_uint(f);
  uint32_t r = (u + 0x7fffu + ((u >> 16) & 1u)) >> 16;
  return (unsigned short)r;
}

// ---------------- pass 1: node partials via MFMA (round-7, passing) --------
#define NPB_M  64
#define NBLKN  ((N_NODES + NPB_M - 1) / NPB_M)   // 782
#define WT_LD  136                               // 128 + 8 pad (ushorts)

__global__ __launch_bounds__(256, 4)
void node_mfma_kernel(const float* __restrict__ node,
                      const float* __restrict__ W1,
                      const float* __restrict__ b1,
                      unsigned short* __restrict__ A_tab,
                      unsigned short* __restrict__ B_tab) {
  __shared__ unsigned short wt[128 * WT_LD];   // 34 KB

  const int tid  = threadIdx.x;
  const int lane = tid & 63;
  const int w    = tid >> 6;          // wave 0..3
  const int c    = lane & 15;
  const int b    = lane >> 4;
  const int v0   = blockIdx.x * NPB_M;

  // stage W' transposed: wt[n'][k] = bf16(W'[k][n'])
  for (int idx = tid; idx < 128 * 128; idx += 256) {
    const int k  = idx >> 7;
    const int np = idx & 127;
    const float wv = W1[((size_t)((np >> 6) * 128 + k)) * HID + (np & 63)];
    wt[np * WT_LD + k] = f2bf_rne(wv);
  }
  __syncthreads();

  // lane's 32-float share of row (v0 + 16w + c): K-step kk uses global
  // float4s (kk*8 + b*2, +1) stored at PRIVATE slots xx[2kk], xx[2kk+1].
  const int vld = min(v0 + w * 16 + c, N_NODES - 1);
  const float4* __restrict__ xrp = (const float4*)(node + (size_t)vld * DIM);
  float4 xx[8];
#pragma unroll
  for (int kk = 0; kk < 4; ++kk) {
    xx[2 * kk]     = xrp[kk * 8 + b * 2];
    xx[2 * kk + 1] = xrp[kk * 8 + b * 2 + 1];
  }

  f32x4 acc[8];
#pragma unroll
  for (int nt = 0; nt < 8; ++nt) acc[nt] = (f32x4){0.f, 0.f, 0.f, 0.f};

#pragma unroll
  for (int kk = 0; kk < 4; ++kk) {
    const float4 x0 = xx[2 * kk];
    const float4 x1 = xx[2 * kk + 1];
    const float xs[8] = { x0.x, x0.y, x0.z, x0.w, x1.x, x1.y, x1.z, x1.w };
    bf16x8 af;
#pragma unroll
    for (int j = 0; j < 8; ++j) af[j] = (short)f2bf_rne(xs[j]);

#pragma unroll
    for (int nt = 0; nt < 8; ++nt) {
      const bf16x8 bf =
          *(const bf16x8*)&wt[(nt * 16 + c) * WT_LD + kk * 32 + b * 8];
      acc[nt] = __builtin_amdgcn_mfma_f32_16x16x32_bf16(af, bf, acc[nt], 0, 0, 0);
    }
  }

  // epilogue: D col = lane&15 (n'), row = b*4 + r
#pragma unroll
  for (int nt = 0; nt < 8; ++nt) {
    const int np = nt * 16 + c;
    const float badd = (np < HID) ? b1[np] : 0.0f;
    unsigned short* __restrict__ base =
        (np < HID) ? (A_tab + np) : (B_tab + (np - HID));
#pragma unroll
    for (int r = 0; r < 4; ++r) {
      const int v = v0 + w * 16 + b * 4 + r;
      if (v < N_NODES) base[(size_t)v * HID] = f2bf_rne(acc[nt][r] + badd);
    }
  }
}

// ---------------- pass 2: depth-2 pipelined gather + MLP + noise ----------
__device__ __forceinline__ void load_rows(int e, const int* __restrict__ ei,
                                          const unsigned short* __restrict__ A_tab,
                                          const unsigned short* __restrict__ B_tab,
                                          uint4 (&av)[8], uint4 (&bv)[8]) {
  const int r = __builtin_nontemporal_load(ei + e);
  const int c = __builtin_nontemporal_load(ei + NE + e);
  const uint4* __restrict__ ap = (const uint4*)(A_tab + (size_t)r * HID);
  const uint4* __restrict__ bp = (const uint4*)(B_tab + (size_t)c * HID);
#pragma unroll
  for (int q = 0; q < 8; ++q) { av[q] = ap[q]; bv[q] = bp[q]; }
}

__device__ __forceinline__ void mlp_noise_store(int e,
                                                const uint4 (&av)[8],
                                                const uint4 (&bv)[8],
                                                const float* __restrict__ W2,
                                                float bias2,
                                                float* __restrict__ out) {
  float logit = bias2;
#pragma unroll
  for (int q = 0; q < 8; ++q) {
    const uint32_t* au = (const uint32_t*)&av[q];
    const uint32_t* bu = (const uint32_t*)&bv[q];
#pragma unroll
    for (int t = 0; t < 4; ++t) {
      const float a0 = __uint_as_float(au[t] << 16);
      const float a1 = __uint_as_float(au[t] & 0xffff0000u);
      const float b0 = __uint_as_float(bu[t] << 16);
      const float b1v = __uint_as_float(bu[t] & 0xffff0000u);
      const int jj = q * 8 + t * 2;
      logit = fmaf(fmaxf(a0 + b0, 0.0f),  W2[jj],     logit);
      logit = fmaf(fmaxf(a1 + b1v, 0.0f), W2[jj + 1], logit);
    }
  }
  const float g1 = gumbel_elem(NK1_0, NK1_1, (uint32_t)e);
  const float g2 = gumbel_elem(NK2_0, NK2_1, (uint32_t)e);
  const float z  = logit + g1 - g2;  // TEMP = 1.0
  __builtin_nontemporal_store(1.0f / (1.0f + __expf(-z)), out + e);
}

// 4 blocks/CU (128-VGPR cap: two 64-dword row buffers + live set, no spill),
// grid 1024 => 262144 threads, 6-7 edges/thread grid-stride. Next edge's 16
// row-loads are issued BEFORE computing the current edge: the ~1100-cycle
// MLP+threefry phase covers the gather round-trip instead of stalling on it.
__global__ __launch_bounds__(256, 4)
void edge_kernel_pipe(const int* __restrict__ ei,
                      const unsigned short* __restrict__ A_tab,
                      const unsigned short* __restrict__ B_tab,
                      const float* __restrict__ W2,
                      const float* __restrict__ b2,
                      float* __restrict__ out) {
  const int tid    = blockIdx.x * blockDim.x + threadIdx.x;
  const int stride = gridDim.x * blockDim.x;   // 262144 < NE: all threads live
  const float bias2 = b2[0];

  uint4 av0[8], bv0[8], av1[8], bv1[8];

  int e = tid;
  load_rows(e, ei, A_tab, B_tab, av0, bv0);

  while (true) {
    const int e1 = e + stride;
    if (e1 < NE) load_rows(e1, ei, A_tab, B_tab, av1, bv1);
    mlp_noise_store(e, av0, bv0, W2, bias2, out);
    if (e1 >= NE) return;

    const int e2 = e1 + stride;
    if (e2 < NE) load_rows(e2, ei, A_tab, B_tab, av0, bv0);
    mlp_noise_store(e1, av1, bv1, W2, bias2, out);
    if (e2 >= NE) return;

    e = e2;
  }
}

// ---------------- fallback (fused, no workspace) ----------------
__global__ __launch_bounds__(256, 4)
void edge_prune_fallback(const float* __restrict__ node,
                         const int*   __restrict__ ei,
                         const float* __restrict__ W1,
                         const float* __restrict__ b1,
                         const float* __restrict__ W2,
                         const float* __restrict__ b2,
                         float*       __restrict__ out) {
  const int tid    = blockIdx.x * blockDim.x + threadIdx.x;
  const int stride = gridDim.x * blockDim.x;
  const float bias2 = b2[0];

  for (int e = tid; e < NE; e += stride) {
    const int r = ei[e];
    const int c = ei[NE + e];
    const float4* __restrict__ up = (const float4*)(node + (size_t)r * DIM);
    const float4* __restrict__ vp = (const float4*)(node + (size_t)c * DIM);

    float h[HID];
#pragma unroll
    for (int j = 0; j < HID; ++j) h[j] = b1[j];

#pragma unroll 1
    for (int dd = 0; dd < DIM / 4; ++dd) {
      const float4 xu = up[dd];
      const float4 xv = vp[dd];
      const float xs[8] = { xu.x, xu.y, xu.z, xu.w, xv.x, xv.y, xv.z, xv.w };
#pragma unroll
      for (int k = 0; k < 8; ++k) {
        const int drow = (k < 4) ? (dd * 4 + k) : (DIM + dd * 4 + (k - 4));
        const float4* __restrict__ wrow = (const float4*)(W1 + drow * HID);
        const float x = xs[k];
#pragma unroll
        for (int j4 = 0; j4 < HID / 4; ++j4) {
          const float4 w = wrow[j4];
          h[j4 * 4 + 0] = fmaf(x, w.x, h[j4 * 4 + 0]);
          h[j4 * 4 + 1] = fmaf(x, w.y, h[j4 * 4 + 1]);
          h[j4 * 4 + 2] = fmaf(x, w.z, h[j4 * 4 + 2]);
          h[j4 * 4 + 3] = fmaf(x, w.w, h[j4 * 4 + 3]);
        }
      }
    }

    float logit = bias2;
#pragma unroll
    for (int j = 0; j < HID; ++j) logit = fmaf(fmaxf(h[j], 0.0f), W2[j], logit);

    const float g1 = gumbel_elem(NK1_0, NK1_1, (uint32_t)e);
    const float g2 = gumbel_elem(NK2_0, NK2_1, (uint32_t)e);
    const float z  = logit + g1 - g2;
    out[e] = 1.0f / (1.0f + __expf(-z));
  }
}

extern "C" void kernel_launch(void* const* d_in, const int* in_sizes, int n_in,
                              void* d_out, int out_size, void* d_ws, size_t ws_size,
                              hipStream_t stream) {
  const float* node = (const float*)d_in[0];
  const int*   ei   = (const int*)  d_in[1];
  const float* W1   = (const float*)d_in[2];
  const float* b1   = (const float*)d_in[3];
  const float* W2   = (const float*)d_in[4];
  const float* b2   = (const float*)d_in[5];
  float* out = (float*)d_out;

  const size_t tab_bytes = (size_t)N_NODES * HID * sizeof(unsigned short);  // 6.4 MB
  if (ws_size >= 2 * tab_bytes) {
    unsigned short* A_tab = (unsigned short*)d_ws;
    unsigned short* B_tab = A_tab + (size_t)N_NODES * HID;
    // pass 1: 782 blocks x 64 nodes, MFMA; node table streamed once (~11 us)
    node_mfma_kernel<<<dim3(NBLKN), dim3(256), 0, stream>>>(
        node, W1, b1, A_tab, B_tab);
    // pass 2: depth-2 pipelined, 4 blocks/CU, grid 1024
    edge_kernel_pipe<<<dim3(1024), dim3(256), 0, stream>>>(
        ei, A_tab, B_tab, W2, b2, out);
  } else {
    edge_prune_fallback<<<dim3(1024), dim3(256), 0, stream>>>(
        node, ei, W1, b1, W2, b2, out);
  }
}

// Round 10
// 84.136 us; speedup vs baseline: 1.3798x; 1.3798x over previous
//
#include <hip/hip_runtime.h>
#include <hip/hip_bf16.h>
#include <stdint.h>

#define N_NODES 50000
#define NE      1600000
#define DIM     128
#define HID     64

typedef __attribute__((ext_vector_type(8))) short bf16x8;
typedef __attribute__((ext_vector_type(4))) float f32x4;

// ---------------- JAX threefry2x32 core (bit-exact) ----------------
struct TF2 { uint32_t a, b; };

__host__ __device__ constexpr uint32_t rotl32(uint32_t x, int d) {
  return (x << d) | (x >> (32 - d));
}

__host__ __device__ constexpr TF2 threefry(uint32_t k0, uint32_t k1,
                                           uint32_t c0, uint32_t c1) {
  uint32_t ks[3] = { k0, k1, k0 ^ k1 ^ 0x1BD11BDAu };
  uint32_t x0 = c0 + ks[0], x1 = c1 + ks[1];
  const int rot[2][4] = { {13, 15, 26, 6}, {17, 29, 16, 24} };
  for (int i = 0; i < 5; ++i) {
    for (int r = 0; r < 4; ++r) {
      x0 += x1;
      x1 = rotl32(x1, rot[i & 1][r]);
      x1 ^= x0;
    }
    x0 += ks[(i + 1) % 3];
    x1 += ks[(i + 2) % 3] + (uint32_t)(i + 1);
  }
  return { x0, x1 };
}

// jax_threefry_partitionable split: nk_j = full threefry(key, (0, j))
constexpr TF2 SPA = threefry(0u, 42u, 0u, 0u);
constexpr TF2 SPB = threefry(0u, 42u, 0u, 1u);
constexpr uint32_t NK1_0 = SPA.a, NK1_1 = SPA.b;
constexpr uint32_t NK2_0 = SPB.a, NK2_1 = SPB.b;

// partitionable random_bits(32): bits = y0 ^ y1 of threefry(key, 0, i)
__device__ inline float gumbel_elem(uint32_t k0, uint32_t k1, uint32_t i) {
  TF2 t = threefry(k0, k1, 0u, i);
  uint32_t bits = t.a ^ t.b;
  float f = __uint_as_float((bits >> 9) | 0x3f800000u) - 1.0f;
  float u = fmaxf(1.1754943508222875e-38f, f + 1.1754943508222875e-38f);
  return -__logf(-__logf(u));   // v_log_f32 ~1 ulp; budget is 2e-2
}

__device__ inline unsigned short f2bf_rne(float f) {
  uint32_t u = __float_as_uint(f);
  uint32_t r = (u + 0x7fffu + ((u >> 16) & 1u)) >> 16;
  return (unsigned short)r;
}

// ---------------- pass 1: node partials via MFMA (round-7, passing) --------
#define NPB_M  64
#define NBLKN  ((N_NODES + NPB_M - 1) / NPB_M)   // 782
#define WT_LD  136                               // 128 + 8 pad (ushorts)

__global__ __launch_bounds__(256, 4)
void node_mfma_kernel(const float* __restrict__ node,
                      const float* __restrict__ W1,
                      const float* __restrict__ b1,
                      unsigned short* __restrict__ A_tab,
                      unsigned short* __restrict__ B_tab) {
  __shared__ unsigned short wt[128 * WT_LD];   // 34 KB

  const int tid  = threadIdx.x;
  const int lane = tid & 63;
  const int w    = tid >> 6;          // wave 0..3
  const int c    = lane & 15;
  const int b    = lane >> 4;
  const int v0   = blockIdx.x * NPB_M;

  // stage W' transposed: wt[n'][k] = bf16(W'[k][n'])
  for (int idx = tid; idx < 128 * 128; idx += 256) {
    const int k  = idx >> 7;
    const int np = idx & 127;
    const float wv = W1[((size_t)((np >> 6) * 128 + k)) * HID + (np & 63)];
    wt[np * WT_LD + k] = f2bf_rne(wv);
  }
  __syncthreads();

  // lane's 32-float share of row (v0 + 16w + c): K-step kk uses global
  // float4s (kk*8 + b*2, +1) stored at PRIVATE slots xx[2kk], xx[2kk+1].
  const int vld = min(v0 + w * 16 + c, N_NODES - 1);
  const float4* __restrict__ xrp = (const float4*)(node + (size_t)vld * DIM);
  float4 xx[8];
#pragma unroll
  for (int kk = 0; kk < 4; ++kk) {
    xx[2 * kk]     = xrp[kk * 8 + b * 2];
    xx[2 * kk + 1] = xrp[kk * 8 + b * 2 + 1];
  }

  f32x4 acc[8];
#pragma unroll
  for (int nt = 0; nt < 8; ++nt) acc[nt] = (f32x4){0.f, 0.f, 0.f, 0.f};

#pragma unroll
  for (int kk = 0; kk < 4; ++kk) {
    const float4 x0 = xx[2 * kk];
    const float4 x1 = xx[2 * kk + 1];
    const float xs[8] = { x0.x, x0.y, x0.z, x0.w, x1.x, x1.y, x1.z, x1.w };
    bf16x8 af;
#pragma unroll
    for (int j = 0; j < 8; ++j) af[j] = (short)f2bf_rne(xs[j]);

#pragma unroll
    for (int nt = 0; nt < 8; ++nt) {
      const bf16x8 bf =
          *(const bf16x8*)&wt[(nt * 16 + c) * WT_LD + kk * 32 + b * 8];
      acc[nt] = __builtin_amdgcn_mfma_f32_16x16x32_bf16(af, bf, acc[nt], 0, 0, 0);
    }
  }

  // epilogue: D col = lane&15 (n'), row = b*4 + r
#pragma unroll
  for (int nt = 0; nt < 8; ++nt) {
    const int np = nt * 16 + c;
    const float badd = (np < HID) ? b1[np] : 0.0f;
    unsigned short* __restrict__ base =
        (np < HID) ? (A_tab + np) : (B_tab + (np - HID));
#pragma unroll
    for (int r = 0; r < 4; ++r) {
      const int v = v0 + w * 16 + b * 4 + r;
      if (v < N_NODES) base[(size_t)v * HID] = f2bf_rne(acc[nt][r] + badd);
    }
  }
}

// ---------------- pass 2: gather-add-relu-dot + noise ----------------------
// __launch_bounds__(256,5): 102-VGPR cap so ALL 16 row-loads can be in
// flight per thread (round-8's (256,6)/85-cap squeezed VGPR to 36 ->
// compiler serialized the gathers into ~6-8-load groups). 5 blocks/CU x
// 20 waves keeps the in-flight edge window at 327K (< r8's 393K) for
// table-reuse distance. Grid 1280 = exactly one resident generation.
__global__ __launch_bounds__(256, 5)
void edge_kernel(const int* __restrict__ ei,
                 const unsigned short* __restrict__ A_tab,
                 const unsigned short* __restrict__ B_tab,
                 const float* __restrict__ W2,
                 const float* __restrict__ b2,
                 float* __restrict__ out) {
  const int tid    = blockIdx.x * blockDim.x + threadIdx.x;
  const int stride = gridDim.x * blockDim.x;
  const float bias2 = b2[0];

  for (int e = tid; e < NE; e += stride) {
    const int r = __builtin_nontemporal_load(ei + e);
    const int c = __builtin_nontemporal_load(ei + NE + e);
    const uint4* __restrict__ ap = (const uint4*)(A_tab + (size_t)r * HID);
    const uint4* __restrict__ bp = (const uint4*)(B_tab + (size_t)c * HID);

    uint4 av[8], bv[8];
#pragma unroll
    for (int q = 0; q < 8; ++q) av[q] = ap[q];
#pragma unroll
    for (int q = 0; q < 8; ++q) bv[q] = bp[q];

    float logit = bias2;
#pragma unroll
    for (int q = 0; q < 8; ++q) {
      const uint32_t* au = (const uint32_t*)&av[q];
      const uint32_t* bu = (const uint32_t*)&bv[q];
#pragma unroll
      for (int t = 0; t < 4; ++t) {
        const float a0 = __uint_as_float(au[t] << 16);
        const float a1 = __uint_as_float(au[t] & 0xffff0000u);
        const float b0 = __uint_as_float(bu[t] << 16);
        const float b1v = __uint_as_float(bu[t] & 0xffff0000u);
        const int jj = q * 8 + t * 2;
        logit = fmaf(fmaxf(a0 + b0, 0.0f),  W2[jj],     logit);
        logit = fmaf(fmaxf(a1 + b1v, 0.0f), W2[jj + 1], logit);
      }
    }

    const float g1 = gumbel_elem(NK1_0, NK1_1, (uint32_t)e);
    const float g2 = gumbel_elem(NK2_0, NK2_1, (uint32_t)e);
    const float z  = logit + g1 - g2;  // TEMP = 1.0
    __builtin_nontemporal_store(1.0f / (1.0f + __expf(-z)), out + e);
  }
}

// ---------------- fallback (fused, no workspace) ----------------
__global__ __launch_bounds__(256, 4)
void edge_prune_fallback(const float* __restrict__ node,
                         const int*   __restrict__ ei,
                         const float* __restrict__ W1,
                         const float* __restrict__ b1,
                         const float* __restrict__ W2,
                         const float* __restrict__ b2,
                         float*       __restrict__ out) {
  const int tid    = blockIdx.x * blockDim.x + threadIdx.x;
  const int stride = gridDim.x * blockDim.x;
  const float bias2 = b2[0];

  for (int e = tid; e < NE; e += stride) {
    const int r = ei[e];
    const int c = ei[NE + e];
    const float4* __restrict__ up = (const float4*)(node + (size_t)r * DIM);
    const float4* __restrict__ vp = (const float4*)(node + (size_t)c * DIM);

    float h[HID];
#pragma unroll
    for (int j = 0; j < HID; ++j) h[j] = b1[j];

#pragma unroll 1
    for (int dd = 0; dd < DIM / 4; ++dd) {
      const float4 xu = up[dd];
      const float4 xv = vp[dd];
      const float xs[8] = { xu.x, xu.y, xu.z, xu.w, xv.x, xv.y, xv.z, xv.w };
#pragma unroll
      for (int k = 0; k < 8; ++k) {
        const int drow = (k < 4) ? (dd * 4 + k) : (DIM + dd * 4 + (k - 4));
        const float4* __restrict__ wrow = (const float4*)(W1 + drow * HID);
        const float x = xs[k];
#pragma unroll
        for (int j4 = 0; j4 < HID / 4; ++j4) {
          const float4 w = wrow[j4];
          h[j4 * 4 + 0] = fmaf(x, w.x, h[j4 * 4 + 0]);
          h[j4 * 4 + 1] = fmaf(x, w.y, h[j4 * 4 + 1]);
          h[j4 * 4 + 2] = fmaf(x, w.z, h[j4 * 4 + 2]);
          h[j4 * 4 + 3] = fmaf(x, w.w, h[j4 * 4 + 3]);
        }
      }
    }

    float logit = bias2;
#pragma unroll
    for (int j = 0; j < HID; ++j) logit = fmaf(fmaxf(h[j], 0.0f), W2[j], logit);

    const float g1 = gumbel_elem(NK1_0, NK1_1, (uint32_t)e);
    const float g2 = gumbel_elem(NK2_0, NK2_1, (uint32_t)e);
    const float z  = logit + g1 - g2;
    out[e] = 1.0f / (1.0f + __expf(-z));
  }
}

extern "C" void kernel_launch(void* const* d_in, const int* in_sizes, int n_in,
                              void* d_out, int out_size, void* d_ws, size_t ws_size,
                              hipStream_t stream) {
  const float* node = (const float*)d_in[0];
  const int*   ei   = (const int*)  d_in[1];
  const float* W1   = (const float*)d_in[2];
  const float* b1   = (const float*)d_in[3];
  const float* W2   = (const float*)d_in[4];
  const float* b2   = (const float*)d_in[5];
  float* out = (float*)d_out;

  const size_t tab_bytes = (size_t)N_NODES * HID * sizeof(unsigned short);  // 6.4 MB
  if (ws_size >= 2 * tab_bytes) {
    unsigned short* A_tab = (unsigned short*)d_ws;
    unsigned short* B_tab = A_tab + (size_t)N_NODES * HID;
    // pass 1: 782 blocks x 64 nodes, MFMA; node table streamed once (~11 us)
    node_mfma_kernel<<<dim3(NBLKN), dim3(256), 0, stream>>>(
        node, W1, b1, A_tab, B_tab);
    // pass 2: 5 blocks/CU, grid 1280, ~4.9 edges/thread grid-stride
    edge_kernel<<<dim3(1280), dim3(256), 0, stream>>>(
        ei, A_tab, B_tab, W2, b2, out);
  } else {
    edge_prune_fallback<<<dim3(1024), dim3(256), 0, stream>>>(
        node, ei, W1, b1, W2, b2, out);
  }
}

// Round 11
// 67.943 us; speedup vs baseline: 1.7086x; 1.2383x over previous
//
#include <hip/hip_runtime.h>
#include <hip/hip_bf16.h>
#include <stdint.h>

#define N_NODES 50000
#define NE      1600000
#define DIM     128
#define HID     64

typedef __attribute__((ext_vector_type(8))) short bf16x8;
typedef __attribute__((ext_vector_type(4))) float f32x4;

// ---------------- JAX threefry2x32 core (bit-exact) ----------------
struct TF2 { uint32_t a, b; };

__host__ __device__ constexpr uint32_t rotl32(uint32_t x, int d) {
  return (x << d) | (x >> (32 - d));
}

__host__ __device__ constexpr TF2 threefry(uint32_t k0, uint32_t k1,
                                           uint32_t c0, uint32_t c1) {
  uint32_t ks[3] = { k0, k1, k0 ^ k1 ^ 0x1BD11BDAu };
  uint32_t x0 = c0 + ks[0], x1 = c1 + ks[1];
  const int rot[2][4] = { {13, 15, 26, 6}, {17, 29, 16, 24} };
  for (int i = 0; i < 5; ++i) {
    for (int r = 0; r < 4; ++r) {
      x0 += x1;
      x1 = rotl32(x1, rot[i & 1][r]);
      x1 ^= x0;
    }
    x0 += ks[(i + 1) % 3];
    x1 += ks[(i + 2) % 3] + (uint32_t)(i + 1);
  }
  return { x0, x1 };
}

// jax_threefry_partitionable split: nk_j = full threefry(key, (0, j))
constexpr TF2 SPA = threefry(0u, 42u, 0u, 0u);
constexpr TF2 SPB = threefry(0u, 42u, 0u, 1u);
constexpr uint32_t NK1_0 = SPA.a, NK1_1 = SPA.b;
constexpr uint32_t NK2_0 = SPB.a, NK2_1 = SPB.b;

// partitionable random_bits(32): bits = y0 ^ y1 of threefry(key, 0, i)
__device__ inline float gumbel_elem(uint32_t k0, uint32_t k1, uint32_t i) {
  TF2 t = threefry(k0, k1, 0u, i);
  uint32_t bits = t.a ^ t.b;
  float f = __uint_as_float((bits >> 9) | 0x3f800000u) - 1.0f;
  float u = fmaxf(1.1754943508222875e-38f, f + 1.1754943508222875e-38f);
  return -__logf(-__logf(u));   // v_log_f32 ~1 ulp; budget is 2e-2
}

__device__ inline unsigned short f2bf_rne(float f) {
  uint32_t u = __float_as_uint(f);
  uint32_t r = (u + 0x7fffu + ((u >> 16) & 1u)) >> 16;
  return (unsigned short)r;
}

// ---------------- pass 1: node partials via MFMA (round-7, passing) --------
#define NPB_M  64
#define NBLKN  ((N_NODES + NPB_M - 1) / NPB_M)   // 782
#define WT_LD  136                               // 128 + 8 pad (ushorts)

__global__ __launch_bounds__(256, 4)
void node_mfma_kernel(const float* __restrict__ node,
                      const float* __restrict__ W1,
                      const float* __restrict__ b1,
                      unsigned short* __restrict__ A_tab,
                      unsigned short* __restrict__ B_tab) {
  __shared__ unsigned short wt[128 * WT_LD];   // 34 KB

  const int tid  = threadIdx.x;
  const int lane = tid & 63;
  const int w    = tid >> 6;          // wave 0..3
  const int c    = lane & 15;
  const int b    = lane >> 4;
  const int v0   = blockIdx.x * NPB_M;

  // stage W' transposed: wt[n'][k] = bf16(W'[k][n'])
  for (int idx = tid; idx < 128 * 128; idx += 256) {
    const int k  = idx >> 7;
    const int np = idx & 127;
    const float wv = W1[((size_t)((np >> 6) * 128 + k)) * HID + (np & 63)];
    wt[np * WT_LD + k] = f2bf_rne(wv);
  }
  __syncthreads();

  // lane's 32-float share of row (v0 + 16w + c)
  const int vld = min(v0 + w * 16 + c, N_NODES - 1);
  const float4* __restrict__ xrp = (const float4*)(node + (size_t)vld * DIM);
  float4 xx[8];
#pragma unroll
  for (int kk = 0; kk < 4; ++kk) {
    xx[2 * kk]     = xrp[kk * 8 + b * 2];
    xx[2 * kk + 1] = xrp[kk * 8 + b * 2 + 1];
  }

  f32x4 acc[8];
#pragma unroll
  for (int nt = 0; nt < 8; ++nt) acc[nt] = (f32x4){0.f, 0.f, 0.f, 0.f};

#pragma unroll
  for (int kk = 0; kk < 4; ++kk) {
    const float4 x0 = xx[2 * kk];
    const float4 x1 = xx[2 * kk + 1];
    const float xs[8] = { x0.x, x0.y, x0.z, x0.w, x1.x, x1.y, x1.z, x1.w };
    bf16x8 af;
#pragma unroll
    for (int j = 0; j < 8; ++j) af[j] = (short)f2bf_rne(xs[j]);

#pragma unroll
    for (int nt = 0; nt < 8; ++nt) {
      const bf16x8 bf =
          *(const bf16x8*)&wt[(nt * 16 + c) * WT_LD + kk * 32 + b * 8];
      acc[nt] = __builtin_amdgcn_mfma_f32_16x16x32_bf16(af, bf, acc[nt], 0, 0, 0);
    }
  }

  // epilogue: D col = lane&15 (n'), row = b*4 + r
#pragma unroll
  for (int nt = 0; nt < 8; ++nt) {
    const int np = nt * 16 + c;
    const float badd = (np < HID) ? b1[np] : 0.0f;
    unsigned short* __restrict__ base =
        (np < HID) ? (A_tab + np) : (B_tab + (np - HID));
#pragma unroll
    for (int r = 0; r < 4; ++r) {
      const int v = v0 + w * 16 + b * 4 + r;
      if (v < N_NODES) base[(size_t)v * HID] = f2bf_rne(acc[nt][r] + badd);
    }
  }
}

// ---------------- pass 2: LDS-DMA gather + MLP + noise ---------------------
// Each WAVE owns 64 edges/batch and a private 16 KB LDS slice; no block
// barriers anywhere (waves free-run, anti-phase naturally; 2 blocks/CU).
// Gather = 16x global_load_lds (per-lane global src, wave-uniform LDS dst,
// lane x 16B): zero data-VGPRs, all 16 x 1KB loads in flight per wave.
// Bank-conflict-free reads via source-side involution (rule #21):
//   segment q stored at slot s = (q&8) | ((q&7) ^ (ed&7)); read applies the
//   same XOR -> matches the conflict-free consecutive baseline (2-way, free).
#define EPB    256                 // edges per block-batch (64 per wave)
#define NBATCH (NE / EPB)          // 6250, exact

__global__ __launch_bounds__(256, 2)
void edge_kernel_dma(const int* __restrict__ ei,
                     const unsigned short* __restrict__ A_tab,
                     const unsigned short* __restrict__ B_tab,
                     const float* __restrict__ W2,
                     const float* __restrict__ b2,
                     float* __restrict__ out) {
  __shared__ uint4 buf[4096];      // 64 KB: 4 waves x 64 edges x 16 x 16B

  const int lane = threadIdx.x & 63;
  const int w    = threadIdx.x >> 6;
  const int l7   = lane & 7;
  const float bias2 = b2[0];

  uint4* wbuf = buf + w * 1024;    // wave-private slice

  for (int bt = blockIdx.x; bt < NBATCH; bt += gridDim.x) {
    const int e0 = bt * EPB + w * 64;      // this wave's 64 edges

    // ---- issue the 16 DMA gathers (all in flight; no data VGPRs) ----
#pragma unroll
    for (int j = 0; j < 16; ++j) {
      const int sgl = j * 64 + lane;                 // slot in wave slice
      const int ed  = sgl >> 4;                      // edge within wave
      const int s   = sgl & 15;                      // slot within edge
      const int q   = (s & 8) | ((s & 7) ^ (ed & 7)); // segment (involution)
      const int idx = __builtin_nontemporal_load(ei + e0 + ed + (q < 8 ? 0 : NE));
      const unsigned short* g =
          (q < 8 ? A_tab : B_tab) + (size_t)idx * HID + (q & 7) * 8;
      __builtin_amdgcn_global_load_lds(
          (const __attribute__((address_space(1))) uint32_t*)g,
          (__attribute__((address_space(3))) uint32_t*)(wbuf + j * 64),
          16, 0, 0);
    }

    // ---- free overlap: threefry noise while the DMA is in flight ----
    const int e = e0 + lane;
    const float g1 = gumbel_elem(NK1_0, NK1_1, (uint32_t)e);
    const float g2 = gumbel_elem(NK2_0, NK2_1, (uint32_t)e);

    asm volatile("s_waitcnt vmcnt(0)" ::: "memory");
    __builtin_amdgcn_sched_barrier(0);

    // ---- MLP from LDS (thread = one edge) ----
    float logit = bias2;
    const int tbase = lane * 16;
#pragma unroll
    for (int qq = 0; qq < 8; ++qq) {
      const int slo = qq ^ l7;
      const uint4 a4 = wbuf[tbase + slo];       // A segment qq
      const uint4 b4 = wbuf[tbase + 8 + slo];   // B segment qq
      const uint32_t* au = (const uint32_t*)&a4;
      const uint32_t* bu = (const uint32_t*)&b4;
#pragma unroll
      for (int t = 0; t < 4; ++t) {
        const float a0 = __uint_as_float(au[t] << 16);
        const float a1 = __uint_as_float(au[t] & 0xffff0000u);
        const float b0 = __uint_as_float(bu[t] << 16);
        const float b1v = __uint_as_float(bu[t] & 0xffff0000u);
        const int jj = qq * 8 + t * 2;
        logit = fmaf(fmaxf(a0 + b0, 0.0f),  W2[jj],     logit);
        logit = fmaf(fmaxf(a1 + b1v, 0.0f), W2[jj + 1], logit);
      }
    }

    const float z = logit + g1 - g2;  // TEMP = 1.0
    __builtin_nontemporal_store(1.0f / (1.0f + __expf(-z)), out + e);
  }
}

// ---------------- fallback (fused, no workspace) ----------------
__global__ __launch_bounds__(256, 4)
void edge_prune_fallback(const float* __restrict__ node,
                         const int*   __restrict__ ei,
                         const float* __restrict__ W1,
                         const float* __restrict__ b1,
                         const float* __restrict__ W2,
                         const float* __restrict__ b2,
                         float*       __restrict__ out) {
  const int tid    = blockIdx.x * blockDim.x + threadIdx.x;
  const int stride = gridDim.x * blockDim.x;
  const float bias2 = b2[0];

  for (int e = tid; e < NE; e += stride) {
    const int r = ei[e];
    const int c = ei[NE + e];
    const float4* __restrict__ up = (const float4*)(node + (size_t)r * DIM);
    const float4* __restrict__ vp = (const float4*)(node + (size_t)c * DIM);

    float h[HID];
#pragma unroll
    for (int j = 0; j < HID; ++j) h[j] = b1[j];

#pragma unroll 1
    for (int dd = 0; dd < DIM / 4; ++dd) {
      const float4 xu = up[dd];
      const float4 xv = vp[dd];
      const float xs[8] = { xu.x, xu.y, xu.z, xu.w, xv.x, xv.y, xv.z, xv.w };
#pragma unroll
      for (int k = 0; k < 8; ++k) {
        const int drow = (k < 4) ? (dd * 4 + k) : (DIM + dd * 4 + (k - 4));
        const float4* __restrict__ wrow = (const float4*)(W1 + drow * HID);
        const float x = xs[k];
#pragma unroll
        for (int j4 = 0; j4 < HID / 4; ++j4) {
          const float4 w = wrow[j4];
          h[j4 * 4 + 0] = fmaf(x, w.x, h[j4 * 4 + 0]);
          h[j4 * 4 + 1] = fmaf(x, w.y, h[j4 * 4 + 1]);
          h[j4 * 4 + 2] = fmaf(x, w.z, h[j4 * 4 + 2]);
          h[j4 * 4 + 3] = fmaf(x, w.w, h[j4 * 4 + 3]);
        }
      }
    }

    float logit = bias2;
#pragma unroll
    for (int j = 0; j < HID; ++j) logit = fmaf(fmaxf(h[j], 0.0f), W2[j], logit);

    const float g1 = gumbel_elem(NK1_0, NK1_1, (uint32_t)e);
    const float g2 = gumbel_elem(NK2_0, NK2_1, (uint32_t)e);
    const float z  = logit + g1 - g2;
    out[e] = 1.0f / (1.0f + __expf(-z));
  }
}

extern "C" void kernel_launch(void* const* d_in, const int* in_sizes, int n_in,
                              void* d_out, int out_size, void* d_ws, size_t ws_size,
                              hipStream_t stream) {
  const float* node = (const float*)d_in[0];
  const int*   ei   = (const int*)  d_in[1];
  const float* W1   = (const float*)d_in[2];
  const float* b1   = (const float*)d_in[3];
  const float* W2   = (const float*)d_in[4];
  const float* b2   = (const float*)d_in[5];
  float* out = (float*)d_out;

  const size_t tab_bytes = (size_t)N_NODES * HID * sizeof(unsigned short);  // 6.4 MB
  if (ws_size >= 2 * tab_bytes) {
    unsigned short* A_tab = (unsigned short*)d_ws;
    unsigned short* B_tab = A_tab + (size_t)N_NODES * HID;
    // pass 1: 782 blocks x 64 nodes, MFMA; node table streamed once (~11 us)
    node_mfma_kernel<<<dim3(NBLKN), dim3(256), 0, stream>>>(
        node, W1, b1, A_tab, B_tab);
    // pass 2: LDS-DMA gather; 512 blocks = 2/CU (64 KB LDS each), no barriers
    edge_kernel_dma<<<dim3(512), dim3(256), 0, stream>>>(
        ei, A_tab, B_tab, W2, b2, out);
  } else {
    edge_prune_fallback<<<dim3(1024), dim3(256), 0, stream>>>(
        node, ei, W1, b1, W2, b2, out);
  }
}